// Round 1
// baseline (11311.281 us; speedup 1.0000x reference)
//
#include <hip/hip_runtime.h>
#include <math.h>

#define NLAYERS 8
#define DMODEL 1024
#define NH 16
#define HD 64
#define FFD 4096
#define SEQ 1024
#define BATCH 2
#define MROWS (BATCH * SEQ)   // 2048
#define LNEPS 1e-5f

// ---------------------------------------------------------------- GEMM
// C[M,N] = A[M,K] @ B[K,N] + bias[N], optional exact-GELU epilogue.
// 64x64 tile, BK=16, 256 threads, 4x4 micro-tile per thread.
#define BM 64
#define BN 64
#define BK 16

__device__ __forceinline__ float gelu_exact(float x) {
    return 0.5f * x * (1.0f + erff(x * 0.70710678118654752f));
}

__global__ __launch_bounds__(256) void gemm_bias(
    const float* __restrict__ A, const float* __restrict__ B,
    const float* __restrict__ bias, float* __restrict__ C,
    int M, int N, int K, int act)
{
    __shared__ float As[BK][BM + 4];   // +4 keeps float4 alignment, 2-way-free banks
    __shared__ float Bs[BK][BN];
    const int tid = threadIdx.x;
    const int bm = blockIdx.y * BM;
    const int bn = blockIdx.x * BN;
    const int tx = tid & 15, ty = tid >> 4;
    const int a_row = tid >> 2, a_col = (tid & 3) << 2;   // A tile: [64 rows][16 k]
    const int b_row = tid >> 4, b_col = (tid & 15) << 2;  // B tile: [16 k][64 cols]

    float acc[4][4] = {};
    for (int k0 = 0; k0 < K; k0 += BK) {
        float4 av = *(const float4*)(A + (size_t)(bm + a_row) * K + k0 + a_col);
        float4 bv = *(const float4*)(B + (size_t)(k0 + b_row) * N + bn + b_col);
        __syncthreads();
        As[a_col + 0][a_row] = av.x;
        As[a_col + 1][a_row] = av.y;
        As[a_col + 2][a_row] = av.z;
        As[a_col + 3][a_row] = av.w;
        *(float4*)&Bs[b_row][b_col] = bv;
        __syncthreads();
#pragma unroll
        for (int kk = 0; kk < BK; ++kk) {
            float4 a4 = *(const float4*)&As[kk][ty << 2];
            float4 b4 = *(const float4*)&Bs[kk][tx << 2];
            float ar[4] = {a4.x, a4.y, a4.z, a4.w};
            float br[4] = {b4.x, b4.y, b4.z, b4.w};
#pragma unroll
            for (int i = 0; i < 4; ++i)
#pragma unroll
                for (int j = 0; j < 4; ++j)
                    acc[i][j] += ar[i] * br[j];
        }
    }
    float4 bias4 = *(const float4*)(bias + bn + (tx << 2));
    float bb[4] = {bias4.x, bias4.y, bias4.z, bias4.w};
#pragma unroll
    for (int i = 0; i < 4; ++i) {
        float4 cv;
        float t[4];
#pragma unroll
        for (int j = 0; j < 4; ++j) {
            t[j] = acc[i][j] + bb[j];
            if (act) t[j] = gelu_exact(t[j]);
        }
        cv.x = t[0]; cv.y = t[1]; cv.z = t[2]; cv.w = t[3];
        *(float4*)(C + (size_t)(bm + (ty << 2) + i) * N + bn + (tx << 2)) = cv;
    }
}

// ---------------------------------------------------------------- PE table
// pe[pos][i] : i<32 -> cos(pos * 10000^(-i/32)) ; else sin(pos * 10000^(-(i-32)/32))
__global__ void pe_fill(float* __restrict__ pe)
{
    int pos = blockIdx.x;
    int i = threadIdx.x;            // 0..63
    int j = i & 31;
    float invf = powf(10000.0f, -(float)j / 32.0f);
    float a = (float)pos * invf;
    pe[pos * HD + i] = (i < 32) ? cosf(a) : sinf(a);
}

// ---------------------------------------------------------------- RoPE (in place)
// out[d<32]  = x[2d]*pe[2d]   - x[2d+1]*pe[2d+1]
// out[d>=32] = x[2j]*pe[2j+1] + x[2j+1]*pe[2j]     (j = d-32)
__global__ __launch_bounds__(64) void rope_kernel(
    float* __restrict__ qp, float* __restrict__ kp, const float* __restrict__ pe)
{
    float* base = blockIdx.y ? kp : qp;
    int bid = blockIdx.x;           // row*NH + h
    int h = bid & (NH - 1);
    int row = bid >> 4;             // b*SEQ + l
    int pos = row & (SEQ - 1);
    __shared__ float xv[HD];
    float* p = base + (size_t)row * DMODEL + h * HD;
    int d = threadIdx.x;
    xv[d] = p[d];
    __syncthreads();
    const float* pr = pe + pos * HD;
    float out;
    if (d < 32) {
        out = xv[2 * d] * pr[2 * d] - xv[2 * d + 1] * pr[2 * d + 1];
    } else {
        int j = d - 32;
        out = xv[2 * j] * pr[2 * j + 1] + xv[2 * j + 1] * pr[2 * j];
    }
    p[d] = out;
}

// ---------------------------------------------------------------- Attention
// One block: (b, h, 8-query tile). Full softmax over SEQ keys with +slope*max(q-k,0).
#define QT 8
#define KT 32

__global__ __launch_bounds__(256) void attn_kernel(
    const float* __restrict__ q, const float* __restrict__ k,
    const float* __restrict__ v, float* __restrict__ o)
{
    __shared__ float qv[QT][HD];
    __shared__ float kt[KT][HD + 1];
    __shared__ float sc[QT][SEQ];
    const int tid = threadIdx.x;
    const int bid = blockIdx.x;
    const int qtile = bid & (SEQ / QT - 1);       // 128
    const int h = (bid >> 7) & (NH - 1);
    const int b = bid >> 11;
    const int q0 = qtile * QT;
    const size_t hoff = (size_t)h * HD;

    if (tid < 128) {
        int qi = tid >> 4, c = (tid & 15) << 2;
        *(float4*)&qv[qi][c] =
            *(const float4*)(q + (size_t)(b * SEQ + q0 + qi) * DMODEL + hoff + c);
    }
    const float slope = exp2f(-0.5f * (float)h);
    const int qi = tid >> 5;        // 0..7
    const int kj = tid & 31;        // 0..31

    for (int kt0 = 0; kt0 < SEQ; kt0 += KT) {
        __syncthreads();
        {
            int row = tid >> 3, col = (tid & 7) << 3;
            const float* kp = k + (size_t)(b * SEQ + kt0 + row) * DMODEL + hoff + col;
            float4 k0v = *(const float4*)kp;
            float4 k1v = *(const float4*)(kp + 4);
            kt[row][col + 0] = k0v.x; kt[row][col + 1] = k0v.y;
            kt[row][col + 2] = k0v.z; kt[row][col + 3] = k0v.w;
            kt[row][col + 4] = k1v.x; kt[row][col + 5] = k1v.y;
            kt[row][col + 6] = k1v.z; kt[row][col + 7] = k1v.w;
        }
        __syncthreads();
        float s = 0.0f;
#pragma unroll
        for (int d = 0; d < HD; ++d) s += qv[qi][d] * kt[kj][d];
        int kpos = kt0 + kj;
        float dist = (float)(q0 + qi - kpos);
        sc[qi][kpos] = s * 0.125f + slope * fmaxf(dist, 0.0f);
    }
    __syncthreads();

    // softmax per query row; 32 lanes per row
    float m = -INFINITY;
    for (int j = kj; j < SEQ; j += 32) m = fmaxf(m, sc[qi][j]);
#pragma unroll
    for (int off = 16; off; off >>= 1) m = fmaxf(m, __shfl_down(m, off, 32));
    m = __shfl(m, 0, 32);
    float s = 0.0f;
    for (int j = kj; j < SEQ; j += 32) {
        float e = __expf(sc[qi][j] - m);
        sc[qi][j] = e;
        s += e;
    }
#pragma unroll
    for (int off = 16; off; off >>= 1) s += __shfl_down(s, off, 32);
    s = __shfl(s, 0, 32);
    const float inv = 1.0f / s;
    __syncthreads();

    // PV: lane owns 2 output dims; whole wave reads one v row per j (coalesced)
    const int d0 = kj << 1;
    float o0 = 0.0f, o1 = 0.0f;
    const float* vp = v + (size_t)(b * SEQ) * DMODEL + hoff + d0;
#pragma unroll 8
    for (int j = 0; j < SEQ; ++j) {
        float w = sc[qi][j];
        float2 vv = *(const float2*)(vp + (size_t)j * DMODEL);
        o0 += w * vv.x;
        o1 += w * vv.y;
    }
    float2 res = {o0 * inv, o1 * inv};
    *(float2*)(o + (size_t)(b * SEQ + q0 + qi) * DMODEL + hoff + d0) = res;
}

// ---------------------------------------------------------------- residual + LayerNorm
// out = LN(x + r) * g + b   (r may be null). One block per row of 1024.
__global__ __launch_bounds__(256) void add_ln_kernel(
    const float* __restrict__ x, const float* __restrict__ r,
    const float* __restrict__ g, const float* __restrict__ b,
    float* __restrict__ out)
{
    __shared__ float rs[4], rq[4], stats[2];
    const int row = blockIdx.x, tid = threadIdx.x;
    const int c = tid << 2;
    float4 v = *(const float4*)(x + (size_t)row * DMODEL + c);
    if (r) {
        float4 rv = *(const float4*)(r + (size_t)row * DMODEL + c);
        v.x += rv.x; v.y += rv.y; v.z += rv.z; v.w += rv.w;
    }
    float s = v.x + v.y + v.z + v.w;
    float q2 = v.x * v.x + v.y * v.y + v.z * v.z + v.w * v.w;
#pragma unroll
    for (int off = 32; off; off >>= 1) {
        s += __shfl_down(s, off, 64);
        q2 += __shfl_down(q2, off, 64);
    }
    const int wid = tid >> 6, lane = tid & 63;
    if (lane == 0) { rs[wid] = s; rq[wid] = q2; }
    __syncthreads();
    if (tid == 0) {
        float ts = rs[0] + rs[1] + rs[2] + rs[3];
        float tq = rq[0] + rq[1] + rq[2] + rq[3];
        float mean = ts * (1.0f / DMODEL);
        stats[0] = mean;
        stats[1] = rsqrtf(tq * (1.0f / DMODEL) - mean * mean + LNEPS);
    }
    __syncthreads();
    const float mean = stats[0], rstd = stats[1];
    float4 gv = *(const float4*)(g + c);
    float4 bv = *(const float4*)(b + c);
    float4 res;
    res.x = (v.x - mean) * rstd * gv.x + bv.x;
    res.y = (v.y - mean) * rstd * gv.y + bv.y;
    res.z = (v.z - mean) * rstd * gv.z + bv.z;
    res.w = (v.w - mean) * rstd * gv.w + bv.w;
    *(float4*)(out + (size_t)row * DMODEL + c) = res;
}

// ---------------------------------------------------------------- host
extern "C" void kernel_launch(void* const* d_in, const int* in_sizes, int n_in,
                              void* d_out, int out_size, void* d_ws, size_t ws_size,
                              hipStream_t stream)
{
    (void)in_sizes; (void)n_in; (void)out_size; (void)ws_size;
    const float* src = (const float*)d_in[0];
    const float* Wq  = (const float*)d_in[1];
    const float* bq  = (const float*)d_in[2];
    const float* Wk  = (const float*)d_in[3];
    const float* bk  = (const float*)d_in[4];
    const float* Wv  = (const float*)d_in[5];
    const float* bv  = (const float*)d_in[6];
    const float* Wo  = (const float*)d_in[7];
    const float* bo  = (const float*)d_in[8];
    const float* W1  = (const float*)d_in[9];
    const float* b1  = (const float*)d_in[10];
    const float* W2  = (const float*)d_in[11];
    const float* b2  = (const float*)d_in[12];
    const float* g1  = (const float*)d_in[13];
    const float* be1 = (const float*)d_in[14];
    const float* g2  = (const float*)d_in[15];
    const float* be2 = (const float*)d_in[16];
    const float* gf  = (const float*)d_in[17];
    const float* bfp = (const float*)d_in[18];
    float* out = (float*)d_out;
    float* ws = (float*)d_ws;

    const size_t NE = (size_t)MROWS * DMODEL;   // 2M floats
    float* x  = ws;                // [0, 2M)
    float* qb = ws + NE;           // [2M, 4M)
    float* kb = ws + 2 * NE;       // [4M, 6M)
    float* vb = ws + 3 * NE;       // [6M, 8M)
    float* ob = ws + 4 * NE;       // [8M, 10M)
    float* h1 = ws + NE;           // FF hidden 8M floats, aliases dead q/k/v/o
    float* t1 = ws + 5 * NE;       // [10M, 12M)
    float* pe = ws + 6 * NE;       // [12M, 12M+64K)

    hipMemcpyAsync(x, src, NE * sizeof(float), hipMemcpyDeviceToDevice, stream);
    pe_fill<<<SEQ, HD, 0, stream>>>(pe);

    dim3 gD(DMODEL / BN, MROWS / BM);   // (16, 32)
    dim3 gF(FFD / BN, MROWS / BM);      // (64, 32)

    for (int l = 0; l < NLAYERS; ++l) {
        const float* wq = Wq + (size_t)l * DMODEL * DMODEL;
        const float* wk = Wk + (size_t)l * DMODEL * DMODEL;
        const float* wv = Wv + (size_t)l * DMODEL * DMODEL;
        const float* wo = Wo + (size_t)l * DMODEL * DMODEL;
        const float* w1 = W1 + (size_t)l * DMODEL * FFD;
        const float* w2 = W2 + (size_t)l * FFD * DMODEL;

        gemm_bias<<<gD, 256, 0, stream>>>(x, wq, bq + l * DMODEL, qb, MROWS, DMODEL, DMODEL, 0);
        gemm_bias<<<gD, 256, 0, stream>>>(x, wk, bk + l * DMODEL, kb, MROWS, DMODEL, DMODEL, 0);
        gemm_bias<<<gD, 256, 0, stream>>>(x, wv, bv + l * DMODEL, vb, MROWS, DMODEL, DMODEL, 0);
        rope_kernel<<<dim3(MROWS * NH, 2), 64, 0, stream>>>(qb, kb, pe);
        attn_kernel<<<BATCH * NH * (SEQ / QT), 256, 0, stream>>>(qb, kb, vb, ob);
        gemm_bias<<<gD, 256, 0, stream>>>(ob, wo, bo + l * DMODEL, t1, MROWS, DMODEL, DMODEL, 0);
        add_ln_kernel<<<MROWS, 256, 0, stream>>>(x, t1, g1 + l * DMODEL, be1 + l * DMODEL, x);
        gemm_bias<<<gF, 256, 0, stream>>>(x, w1, b1 + l * FFD, h1, MROWS, FFD, DMODEL, 1);
        gemm_bias<<<gD, 256, 0, stream>>>(h1, w2, b2 + l * DMODEL, t1, MROWS, DMODEL, FFD, 0);
        add_ln_kernel<<<MROWS, 256, 0, stream>>>(x, t1, g2 + l * DMODEL, be2 + l * DMODEL, x);
    }
    add_ln_kernel<<<MROWS, 256, 0, stream>>>(x, nullptr, gf, bfp, out);
}

// Round 2
// 6787.859 us; speedup vs baseline: 1.6664x; 1.6664x over previous
//
#include <hip/hip_runtime.h>
#include <hip/hip_bf16.h>
#include <math.h>

#define NLAYERS 8
#define DMODEL 1024
#define NH 16
#define HD 64
#define FFD 4096
#define SEQ 1024
#define BATCH 2
#define MROWS (BATCH * SEQ)   // 2048
#define LNEPS 1e-5f
#define LDQ 3072              // fused qkv row stride

typedef short bf16x8 __attribute__((ext_vector_type(8)));
typedef float f32x4 __attribute__((ext_vector_type(4)));

__device__ __forceinline__ unsigned short f2bf(float v) {
    unsigned u = __float_as_uint(v);
    u += 0x7fffu + ((u >> 16) & 1u);   // RNE
    return (unsigned short)(u >> 16);
}

__device__ __forceinline__ float gelu_exact(float x) {
    return 0.5f * x * (1.0f + erff(x * 0.70710678118654752f));
}

// ---------------------------------------------------------------- MFMA GEMM (TN)
// C[M,N] = A[M,K] (bf16, row-major) @ Bt[N,K]^T (bf16) + bias.
// 128x128 tile, BK=32, 4 waves each 64x64 via 4x4 mfma_f32_16x16x32_bf16.
// A-frag:  A[m=lane&15][k=quad*8+j]      (16B contiguous in LDS row-major [r][32])
// B-frag:  B[k=quad*8+j][n=lane&15] = Bt[n][k]  (same layout from Bt tile)
// C/D:     row = quad*4 + reg, col = lane&15    (m89-verified)
#define TMT 128
#define TNT 128
#define TKT 32

__global__ __launch_bounds__(256) void gemm_tn(
    const short* __restrict__ A, const short* __restrict__ Bt,
    const float* __restrict__ bias, float* __restrict__ Cf,
    short* __restrict__ Cb, int M, int N, int K, int ldc, int act)
{
    __shared__ __align__(16) short As[TMT * TKT];
    __shared__ __align__(16) short Bs[TNT * TKT];
    const int tid = threadIdx.x;
    const int bm = blockIdx.y * TMT;
    const int bn = blockIdx.x * TNT;
    const int wave = tid >> 6, lane = tid & 63;
    const int wm = (wave >> 1) << 6, wn = (wave & 1) << 6;
    const int lr = lane & 15, quad = lane >> 4;

    const int srow = tid >> 2;            // 0..63
    const int scol = (tid & 3) << 3;      // 0,8,16,24 (bf16 elems)
    const short* ag = A  + (size_t)(bm + srow) * K + scol;
    const short* bg = Bt + (size_t)(bn + srow) * K + scol;
    short* asl = As + srow * TKT + scol;
    short* bsl = Bs + srow * TKT + scol;

    f32x4 acc[4][4] = {};
    for (int k0 = 0; k0 < K; k0 += TKT) {
        float4 a0 = *(const float4*)(ag + k0);
        float4 a1 = *(const float4*)(ag + (size_t)64 * K + k0);
        float4 b0 = *(const float4*)(bg + k0);
        float4 b1 = *(const float4*)(bg + (size_t)64 * K + k0);
        __syncthreads();
        *(float4*)asl = a0;
        *(float4*)(asl + 64 * TKT) = a1;
        *(float4*)bsl = b0;
        *(float4*)(bsl + 64 * TKT) = b1;
        __syncthreads();
        bf16x8 af[4], bfr[4];
#pragma unroll
        for (int i = 0; i < 4; ++i) {
            af[i]  = *(const bf16x8*)(As + (wm + i * 16 + lr) * TKT + (quad << 3));
            bfr[i] = *(const bf16x8*)(Bs + (wn + i * 16 + lr) * TKT + (quad << 3));
        }
#pragma unroll
        for (int i = 0; i < 4; ++i)
#pragma unroll
            for (int j = 0; j < 4; ++j)
                acc[i][j] = __builtin_amdgcn_mfma_f32_16x16x32_bf16(
                    af[i], bfr[j], acc[i][j], 0, 0, 0);
    }
#pragma unroll
    for (int j = 0; j < 4; ++j) {
        const int col = bn + wn + j * 16 + lr;
        const float bj = bias[col];
#pragma unroll
        for (int i = 0; i < 4; ++i) {
            const int rowb = bm + wm + i * 16 + (quad << 2);
#pragma unroll
            for (int r = 0; r < 4; ++r) {
                float v = acc[i][j][r] + bj;
                if (act) v = gelu_exact(v);
                if (Cb) Cb[(size_t)(rowb + r) * ldc + col] = (short)f2bf(v);
                else    Cf[(size_t)(rowb + r) * ldc + col] = v;
            }
        }
    }
}

// ---------------------------------------------------------------- transpose + fp32->bf16
// in [R][C] fp32 row-major -> out [C][R] bf16
__global__ __launch_bounds__(256) void transpose_bf16(
    const float* __restrict__ in, short* __restrict__ out, int R, int C)
{
    __shared__ float t[32][33];
    const int tid = threadIdx.x;
    const int rt = blockIdx.y << 5, ct = blockIdx.x << 5;
    const int r = tid >> 3, c4 = (tid & 7) << 2;
    float4 v = *(const float4*)(in + (size_t)(rt + r) * C + ct + c4);
    t[r][c4 + 0] = v.x; t[r][c4 + 1] = v.y; t[r][c4 + 2] = v.z; t[r][c4 + 3] = v.w;
    __syncthreads();
    unsigned short s0 = f2bf(t[c4 + 0][r]);
    unsigned short s1 = f2bf(t[c4 + 1][r]);
    unsigned short s2 = f2bf(t[c4 + 2][r]);
    unsigned short s3 = f2bf(t[c4 + 3][r]);
    uint2 p;
    p.x = (unsigned)s0 | ((unsigned)s1 << 16);
    p.y = (unsigned)s2 | ((unsigned)s3 << 16);
    *(uint2*)(out + (size_t)(ct + r) * R + rt + c4) = p;
}

// ---------------------------------------------------------------- small utils
__global__ void stack_bias(const float* __restrict__ bq, const float* __restrict__ bk,
                           const float* __restrict__ bv, float* __restrict__ out)
{
    int i = blockIdx.x * 256 + threadIdx.x;   // 0..3071
    float v = (i < 1024) ? bq[i] : (i < 2048) ? bk[i - 1024] : bv[i - 2048];
    out[i] = v;
}

__global__ void conv_bf16(const float* __restrict__ in, short* __restrict__ out, int n)
{
    int i = (blockIdx.x * 256 + threadIdx.x) << 2;
    if (i < n) {
        float4 v = *(const float4*)(in + i);
        uint2 p;
        p.x = (unsigned)f2bf(v.x) | ((unsigned)f2bf(v.y) << 16);
        p.y = (unsigned)f2bf(v.z) | ((unsigned)f2bf(v.w) << 16);
        *(uint2*)(out + i) = p;
    }
}

// ---------------------------------------------------------------- PE table
__global__ void pe_fill(float* __restrict__ pe)
{
    int pos = blockIdx.x;
    int i = threadIdx.x;            // 0..63
    int j = i & 31;
    float invf = powf(10000.0f, -(float)j / 32.0f);
    float a = (float)pos * invf;
    pe[pos * HD + i] = (i < 32) ? cosf(a) : sinf(a);
}

// ---------------------------------------------------------------- RoPE on fused qkv (q: col 0, k: col 1024)
__global__ __launch_bounds__(64) void rope_kernel(
    float* __restrict__ xqkv, const float* __restrict__ pe)
{
    float* base = xqkv + (blockIdx.y ? DMODEL : 0);
    int bid = blockIdx.x;           // row*NH + h
    int h = bid & (NH - 1);
    int row = bid >> 4;             // b*SEQ + l
    int pos = row & (SEQ - 1);
    __shared__ float xv[HD];
    float* p = base + (size_t)row * LDQ + h * HD;
    int d = threadIdx.x;
    xv[d] = p[d];
    __syncthreads();
    const float* pr = pe + pos * HD;
    float out;
    if (d < 32) {
        out = xv[2 * d] * pr[2 * d] - xv[2 * d + 1] * pr[2 * d + 1];
    } else {
        int j = d - 32;
        out = xv[2 * j] * pr[2 * j + 1] + xv[2 * j + 1] * pr[2 * j];
    }
    p[d] = out;
}

// ---------------------------------------------------------------- Attention (fp32 in, bf16 out)
#define QT 8
#define KT 32

__global__ __launch_bounds__(256) void attn_kernel(
    const float* __restrict__ xqkv, short* __restrict__ ob)
{
    __shared__ float qv[QT][HD];
    __shared__ float kt[KT][HD + 1];
    __shared__ float sc[QT][SEQ];
    const float* q = xqkv;
    const float* k = xqkv + DMODEL;
    const float* v = xqkv + 2 * DMODEL;
    const int tid = threadIdx.x;
    const int bid = blockIdx.x;
    const int qtile = bid & (SEQ / QT - 1);       // 128
    const int h = (bid >> 7) & (NH - 1);
    const int b = bid >> 11;
    const int q0 = qtile * QT;
    const size_t hoff = (size_t)h * HD;

    if (tid < 128) {
        int qi = tid >> 4, c = (tid & 15) << 2;
        *(float4*)&qv[qi][c] =
            *(const float4*)(q + (size_t)(b * SEQ + q0 + qi) * LDQ + hoff + c);
    }
    const float slope = exp2f(-0.5f * (float)h);
    const int qi = tid >> 5;        // 0..7
    const int kj = tid & 31;        // 0..31

    for (int kt0 = 0; kt0 < SEQ; kt0 += KT) {
        __syncthreads();
        {
            int row = tid >> 3, col = (tid & 7) << 3;
            const float* kp = k + (size_t)(b * SEQ + kt0 + row) * LDQ + hoff + col;
            float4 k0v = *(const float4*)kp;
            float4 k1v = *(const float4*)(kp + 4);
            kt[row][col + 0] = k0v.x; kt[row][col + 1] = k0v.y;
            kt[row][col + 2] = k0v.z; kt[row][col + 3] = k0v.w;
            kt[row][col + 4] = k1v.x; kt[row][col + 5] = k1v.y;
            kt[row][col + 6] = k1v.z; kt[row][col + 7] = k1v.w;
        }
        __syncthreads();
        float s = 0.0f;
#pragma unroll
        for (int d = 0; d < HD; ++d) s += qv[qi][d] * kt[kj][d];
        int kpos = kt0 + kj;
        float dist = (float)(q0 + qi - kpos);
        sc[qi][kpos] = s * 0.125f + slope * fmaxf(dist, 0.0f);
    }
    __syncthreads();

    float m = -INFINITY;
    for (int j = kj; j < SEQ; j += 32) m = fmaxf(m, sc[qi][j]);
#pragma unroll
    for (int off = 16; off; off >>= 1) m = fmaxf(m, __shfl_down(m, off, 32));
    m = __shfl(m, 0, 32);
    float s = 0.0f;
    for (int j = kj; j < SEQ; j += 32) {
        float e = __expf(sc[qi][j] - m);
        sc[qi][j] = e;
        s += e;
    }
#pragma unroll
    for (int off = 16; off; off >>= 1) s += __shfl_down(s, off, 32);
    s = __shfl(s, 0, 32);
    const float inv = 1.0f / s;
    __syncthreads();

    const int d0 = kj << 1;
    float o0 = 0.0f, o1 = 0.0f;
    const float* vp = v + (size_t)(b * SEQ) * LDQ + hoff + d0;
#pragma unroll 8
    for (int j = 0; j < SEQ; ++j) {
        float w = sc[qi][j];
        float2 vv = *(const float2*)(vp + (size_t)j * LDQ);
        o0 += w * vv.x;
        o1 += w * vv.y;
    }
    unsigned pk = (unsigned)f2bf(o0 * inv) | ((unsigned)f2bf(o1 * inv) << 16);
    *(unsigned*)(ob + (size_t)(b * SEQ + q0 + qi) * DMODEL + hoff + d0) = pk;
}

// ---------------------------------------------------------------- residual + LayerNorm (+ bf16 mirror)
__global__ __launch_bounds__(256) void add_ln_kernel(
    const float* __restrict__ x, const float* __restrict__ r,
    const float* __restrict__ g, const float* __restrict__ b,
    float* __restrict__ out, short* __restrict__ outb)
{
    __shared__ float rs[4], rq[4], stats[2];
    const int row = blockIdx.x, tid = threadIdx.x;
    const int c = tid << 2;
    float4 v = *(const float4*)(x + (size_t)row * DMODEL + c);
    if (r) {
        float4 rv = *(const float4*)(r + (size_t)row * DMODEL + c);
        v.x += rv.x; v.y += rv.y; v.z += rv.z; v.w += rv.w;
    }
    float s = v.x + v.y + v.z + v.w;
    float q2 = v.x * v.x + v.y * v.y + v.z * v.z + v.w * v.w;
#pragma unroll
    for (int off = 32; off; off >>= 1) {
        s += __shfl_down(s, off, 64);
        q2 += __shfl_down(q2, off, 64);
    }
    const int wid = tid >> 6, lane = tid & 63;
    if (lane == 0) { rs[wid] = s; rq[wid] = q2; }
    __syncthreads();
    if (tid == 0) {
        float ts = rs[0] + rs[1] + rs[2] + rs[3];
        float tq = rq[0] + rq[1] + rq[2] + rq[3];
        float mean = ts * (1.0f / DMODEL);
        stats[0] = mean;
        stats[1] = rsqrtf(tq * (1.0f / DMODEL) - mean * mean + LNEPS);
    }
    __syncthreads();
    const float mean = stats[0], rstd = stats[1];
    float4 gv = *(const float4*)(g + c);
    float4 bv = *(const float4*)(b + c);
    float4 res;
    res.x = (v.x - mean) * rstd * gv.x + bv.x;
    res.y = (v.y - mean) * rstd * gv.y + bv.y;
    res.z = (v.z - mean) * rstd * gv.z + bv.z;
    res.w = (v.w - mean) * rstd * gv.w + bv.w;
    *(float4*)(out + (size_t)row * DMODEL + c) = res;
    if (outb) {
        uint2 p;
        p.x = (unsigned)f2bf(res.x) | ((unsigned)f2bf(res.y) << 16);
        p.y = (unsigned)f2bf(res.z) | ((unsigned)f2bf(res.w) << 16);
        *(uint2*)(outb + (size_t)row * DMODEL + c) = p;
    }
}

// ---------------------------------------------------------------- host
extern "C" void kernel_launch(void* const* d_in, const int* in_sizes, int n_in,
                              void* d_out, int out_size, void* d_ws, size_t ws_size,
                              hipStream_t stream)
{
    (void)in_sizes; (void)n_in; (void)out_size; (void)ws_size;
    const float* src = (const float*)d_in[0];
    const float* Wq  = (const float*)d_in[1];
    const float* bq  = (const float*)d_in[2];
    const float* Wk  = (const float*)d_in[3];
    const float* bk  = (const float*)d_in[4];
    const float* Wv  = (const float*)d_in[5];
    const float* bv  = (const float*)d_in[6];
    const float* Wo  = (const float*)d_in[7];
    const float* bo  = (const float*)d_in[8];
    const float* W1  = (const float*)d_in[9];
    const float* b1  = (const float*)d_in[10];
    const float* W2  = (const float*)d_in[11];
    const float* b2  = (const float*)d_in[12];
    const float* g1  = (const float*)d_in[13];
    const float* be1 = (const float*)d_in[14];
    const float* g2  = (const float*)d_in[15];
    const float* be2 = (const float*)d_in[16];
    const float* gf  = (const float*)d_in[17];
    const float* bfp = (const float*)d_in[18];
    float* out = (float*)d_out;

    char* p = (char*)d_ws;
    auto carve = [&](size_t bytes) -> char* {
        char* r = p; p += (bytes + 255) & ~(size_t)255; return r;
    };
    float* x    = (float*)carve((size_t)MROWS * DMODEL * 4);
    float* t1   = (float*)carve((size_t)MROWS * DMODEL * 4);
    float* xqkv = (float*)carve((size_t)MROWS * LDQ * 4);
    float* pe   = (float*)carve((size_t)SEQ * HD * 4);
    float* bqkv = (float*)carve((size_t)LDQ * 4);
    short* xb   = (short*)carve((size_t)MROWS * DMODEL * 2);
    short* obb  = (short*)carve((size_t)MROWS * DMODEL * 2);
    short* h1b  = (short*)carve((size_t)MROWS * FFD * 2);
    short* wtqkv= (short*)carve((size_t)3 * DMODEL * DMODEL * 2);
    short* wto  = (short*)carve((size_t)DMODEL * DMODEL * 2);
    short* wt1  = (short*)carve((size_t)DMODEL * FFD * 2);
    short* wt2  = (short*)carve((size_t)DMODEL * FFD * 2);

    hipMemcpyAsync(x, src, (size_t)MROWS * DMODEL * 4, hipMemcpyDeviceToDevice, stream);
    conv_bf16<<<MROWS * DMODEL / 4 / 256, 256, 0, stream>>>(src, xb, MROWS * DMODEL);
    pe_fill<<<SEQ, HD, 0, stream>>>(pe);

    const size_t DD = (size_t)DMODEL * DMODEL;
    for (int l = 0; l < NLAYERS; ++l) {
        transpose_bf16<<<dim3(32, 32), 256, 0, stream>>>(Wq + l * DD, wtqkv,          DMODEL, DMODEL);
        transpose_bf16<<<dim3(32, 32), 256, 0, stream>>>(Wk + l * DD, wtqkv + DD,     DMODEL, DMODEL);
        transpose_bf16<<<dim3(32, 32), 256, 0, stream>>>(Wv + l * DD, wtqkv + 2 * DD, DMODEL, DMODEL);
        transpose_bf16<<<dim3(32, 32), 256, 0, stream>>>(Wo + l * DD, wto, DMODEL, DMODEL);
        transpose_bf16<<<dim3(128, 32), 256, 0, stream>>>(W1 + (size_t)l * DMODEL * FFD, wt1, DMODEL, FFD);
        transpose_bf16<<<dim3(32, 128), 256, 0, stream>>>(W2 + (size_t)l * FFD * DMODEL, wt2, FFD, DMODEL);
        stack_bias<<<12, 256, 0, stream>>>(bq + l * DMODEL, bk + l * DMODEL, bv + l * DMODEL, bqkv);

        gemm_tn<<<dim3(LDQ / TNT, MROWS / TMT), 256, 0, stream>>>(
            xb, wtqkv, bqkv, xqkv, nullptr, MROWS, LDQ, DMODEL, LDQ, 0);
        rope_kernel<<<dim3(MROWS * NH, 2), 64, 0, stream>>>(xqkv, pe);
        attn_kernel<<<BATCH * NH * (SEQ / QT), 256, 0, stream>>>(xqkv, obb);
        gemm_tn<<<dim3(DMODEL / TNT, MROWS / TMT), 256, 0, stream>>>(
            obb, wto, bo + l * DMODEL, t1, nullptr, MROWS, DMODEL, DMODEL, DMODEL, 0);
        add_ln_kernel<<<MROWS, 256, 0, stream>>>(x, t1, g1 + l * DMODEL, be1 + l * DMODEL, x, xb);
        gemm_tn<<<dim3(FFD / TNT, MROWS / TMT), 256, 0, stream>>>(
            xb, wt1, b1 + l * FFD, nullptr, h1b, MROWS, FFD, DMODEL, FFD, 1);
        gemm_tn<<<dim3(DMODEL / TNT, MROWS / TMT), 256, 0, stream>>>(
            h1b, wt2, b2 + l * DMODEL, t1, nullptr, MROWS, DMODEL, FFD, DMODEL, 0);
        add_ln_kernel<<<MROWS, 256, 0, stream>>>(x, t1, g2 + l * DMODEL, be2 + l * DMODEL, x, xb);
    }
    add_ln_kernel<<<MROWS, 256, 0, stream>>>(x, nullptr, gf, bfp, out, nullptr);
}

// Round 3
// 2664.368 us; speedup vs baseline: 4.2454x; 2.5476x over previous
//
#include <hip/hip_runtime.h>
#include <hip/hip_bf16.h>
#include <math.h>

#define NLAYERS 8
#define DMODEL 1024
#define NH 16
#define HD 64
#define FFD 4096
#define SEQ 1024
#define BATCH 2
#define MROWS (BATCH * SEQ)   // 2048
#define LNEPS 1e-5f
#define LDQ 3072              // fused qkv row stride

typedef short bf16x8 __attribute__((ext_vector_type(8)));
typedef float f32x4 __attribute__((ext_vector_type(4)));

__device__ __forceinline__ unsigned short f2bf(float v) {
    unsigned u = __float_as_uint(v);
    u += 0x7fffu + ((u >> 16) & 1u);   // RNE
    return (unsigned short)(u >> 16);
}

__device__ __forceinline__ float gelu_exact(float x) {
    return 0.5f * x * (1.0f + erff(x * 0.70710678118654752f));
}

// ---------------------------------------------------------------- MFMA GEMM (TN)
// C[M,N] = A[M,K] (bf16, row-major) @ Bt[N,K]^T (bf16) + bias.
// 128x128 tile, BK=32, 4 waves each 64x64 via 4x4 mfma_f32_16x16x32_bf16.
#define TMT 128
#define TNT 128
#define TKT 32

__global__ __launch_bounds__(256) void gemm_tn(
    const short* __restrict__ A, const short* __restrict__ Bt,
    const float* __restrict__ bias, float* __restrict__ Cf,
    short* __restrict__ Cb, int M, int N, int K, int ldc, int act)
{
    __shared__ __align__(16) short As[TMT * TKT];
    __shared__ __align__(16) short Bs[TNT * TKT];
    const int tid = threadIdx.x;
    const int bm = blockIdx.y * TMT;
    const int bn = blockIdx.x * TNT;
    const int wave = tid >> 6, lane = tid & 63;
    const int wm = (wave >> 1) << 6, wn = (wave & 1) << 6;
    const int lr = lane & 15, quad = lane >> 4;

    const int srow = tid >> 2;            // 0..63
    const int scol = (tid & 3) << 3;      // 0,8,16,24 (bf16 elems)
    const short* ag = A  + (size_t)(bm + srow) * K + scol;
    const short* bg = Bt + (size_t)(bn + srow) * K + scol;
    short* asl = As + srow * TKT + scol;
    short* bsl = Bs + srow * TKT + scol;

    f32x4 acc[4][4] = {};
    for (int k0 = 0; k0 < K; k0 += TKT) {
        float4 a0 = *(const float4*)(ag + k0);
        float4 a1 = *(const float4*)(ag + (size_t)64 * K + k0);
        float4 b0 = *(const float4*)(bg + k0);
        float4 b1 = *(const float4*)(bg + (size_t)64 * K + k0);
        __syncthreads();
        *(float4*)asl = a0;
        *(float4*)(asl + 64 * TKT) = a1;
        *(float4*)bsl = b0;
        *(float4*)(bsl + 64 * TKT) = b1;
        __syncthreads();
        bf16x8 af[4], bfr[4];
#pragma unroll
        for (int i = 0; i < 4; ++i) {
            af[i]  = *(const bf16x8*)(As + (wm + i * 16 + lr) * TKT + (quad << 3));
            bfr[i] = *(const bf16x8*)(Bs + (wn + i * 16 + lr) * TKT + (quad << 3));
        }
#pragma unroll
        for (int i = 0; i < 4; ++i)
#pragma unroll
            for (int j = 0; j < 4; ++j)
                acc[i][j] = __builtin_amdgcn_mfma_f32_16x16x32_bf16(
                    af[i], bfr[j], acc[i][j], 0, 0, 0);
    }
#pragma unroll
    for (int j = 0; j < 4; ++j) {
        const int col = bn + wn + j * 16 + lr;
        const float bj = bias[col];
#pragma unroll
        for (int i = 0; i < 4; ++i) {
            const int rowb = bm + wm + i * 16 + (quad << 2);
#pragma unroll
            for (int r = 0; r < 4; ++r) {
                float v = acc[i][j][r] + bj;
                if (act) v = gelu_exact(v);
                if (Cb) Cb[(size_t)(rowb + r) * ldc + col] = (short)f2bf(v);
                else    Cf[(size_t)(rowb + r) * ldc + col] = v;
            }
        }
    }
}

// ---------------------------------------------------------------- transpose + fp32->bf16
__global__ __launch_bounds__(256) void transpose_bf16(
    const float* __restrict__ in, short* __restrict__ out, int R, int C)
{
    __shared__ float t[32][33];
    const int tid = threadIdx.x;
    const int rt = blockIdx.y << 5, ct = blockIdx.x << 5;
    const int r = tid >> 3, c4 = (tid & 7) << 2;
    float4 v = *(const float4*)(in + (size_t)(rt + r) * C + ct + c4);
    t[r][c4 + 0] = v.x; t[r][c4 + 1] = v.y; t[r][c4 + 2] = v.z; t[r][c4 + 3] = v.w;
    __syncthreads();
    unsigned short s0 = f2bf(t[c4 + 0][r]);
    unsigned short s1 = f2bf(t[c4 + 1][r]);
    unsigned short s2 = f2bf(t[c4 + 2][r]);
    unsigned short s3 = f2bf(t[c4 + 3][r]);
    uint2 p;
    p.x = (unsigned)s0 | ((unsigned)s1 << 16);
    p.y = (unsigned)s2 | ((unsigned)s3 << 16);
    *(uint2*)(out + (size_t)(ct + r) * R + rt + c4) = p;
}

// ---------------------------------------------------------------- small utils
__global__ void stack_bias(const float* __restrict__ bq, const float* __restrict__ bk,
                           const float* __restrict__ bv, float* __restrict__ out)
{
    int i = blockIdx.x * 256 + threadIdx.x;   // 0..3071
    float v = (i < 1024) ? bq[i] : (i < 2048) ? bk[i - 1024] : bv[i - 2048];
    out[i] = v;
}

__global__ void conv_bf16(const float* __restrict__ in, short* __restrict__ out, int n)
{
    int i = (blockIdx.x * 256 + threadIdx.x) << 2;
    if (i < n) {
        float4 v = *(const float4*)(in + i);
        uint2 p;
        p.x = (unsigned)f2bf(v.x) | ((unsigned)f2bf(v.y) << 16);
        p.y = (unsigned)f2bf(v.z) | ((unsigned)f2bf(v.w) << 16);
        *(uint2*)(out + i) = p;
    }
}

// ---------------------------------------------------------------- PE table
__global__ void pe_fill(float* __restrict__ pe)
{
    int pos = blockIdx.x;
    int i = threadIdx.x;            // 0..63
    int j = i & 31;
    float invf = powf(10000.0f, -(float)j / 32.0f);
    float a = (float)pos * invf;
    pe[pos * HD + i] = (i < 32) ? cosf(a) : sinf(a);
}

// ---------------------------------------------------------------- RoPE on fused qkv
__global__ __launch_bounds__(64) void rope_kernel(
    float* __restrict__ xqkv, const float* __restrict__ pe)
{
    float* base = xqkv + (blockIdx.y ? DMODEL : 0);
    int bid = blockIdx.x;           // row*NH + h
    int h = bid & (NH - 1);
    int row = bid >> 4;             // b*SEQ + l
    int pos = row & (SEQ - 1);
    __shared__ float xv[HD];
    float* p = base + (size_t)row * LDQ + h * HD;
    int d = threadIdx.x;
    xv[d] = p[d];
    __syncthreads();
    const float* pr = pe + pos * HD;
    float out;
    if (d < 32) {
        out = xv[2 * d] * pr[2 * d] - xv[2 * d + 1] * pr[2 * d + 1];
    } else {
        int j = d - 32;
        out = xv[2 * j] * pr[2 * j + 1] + xv[2 * j + 1] * pr[2 * j];
    }
    p[d] = out;
}

// ---------------------------------------------------------------- MFMA flash attention
// Block = (b, h, 64-query tile); 4 waves, each owns 16 q-rows.
// K-tiles of 64 staged fp32->bf16; V staged transposed (B-frag needs
// 8 consecutive k=key elems). Row pad 72 shorts (144B = 36 dwords ->
// lane row-stride 4 banks mod 32, free 2-way conflict only).
#define ATQ 64
#define ATK 64
#define APAD 72

__global__ __launch_bounds__(256) void attn_mfma(
    const float* __restrict__ xqkv, short* __restrict__ ob)
{
    __shared__ __align__(16) short Qs[ATQ * APAD];
    __shared__ __align__(16) short Ks[ATK * APAD];
    __shared__ __align__(16) short Vt[HD * APAD];
    __shared__ __align__(16) short Ps[4 * 16 * APAD];

    const int tid = threadIdx.x;
    const int bid = blockIdx.x;
    const int qtile = bid & 15;
    const int h = (bid >> 4) & 15;
    const int b = bid >> 8;
    const int q0 = qtile * ATQ;
    const size_t hoff = (size_t)h * HD;
    const float* qg = xqkv;
    const float* kg = xqkv + DMODEL;
    const float* vg = xqkv + 2 * DMODEL;

    const int wave = tid >> 6, lane = tid & 63;
    const int lr = lane & 15, quad = lane >> 4;
    const int srow = tid >> 2;          // 0..63
    const int sc0 = (tid & 3) << 4;     // 0,16,32,48

    // ---- stage Q once (fp32 -> bf16)
    {
        const float* p = qg + (size_t)(b * SEQ + q0 + srow) * LDQ + hoff + sc0;
        float4 v0 = *(const float4*)(p);
        float4 v1 = *(const float4*)(p + 4);
        float4 v2 = *(const float4*)(p + 8);
        float4 v3 = *(const float4*)(p + 12);
        bf16x8 a, c;
        a[0] = f2bf(v0.x); a[1] = f2bf(v0.y); a[2] = f2bf(v0.z); a[3] = f2bf(v0.w);
        a[4] = f2bf(v1.x); a[5] = f2bf(v1.y); a[6] = f2bf(v1.z); a[7] = f2bf(v1.w);
        c[0] = f2bf(v2.x); c[1] = f2bf(v2.y); c[2] = f2bf(v2.z); c[3] = f2bf(v2.w);
        c[4] = f2bf(v3.x); c[5] = f2bf(v3.y); c[6] = f2bf(v3.z); c[7] = f2bf(v3.w);
        *(bf16x8*)(Qs + srow * APAD + sc0) = a;
        *(bf16x8*)(Qs + srow * APAD + sc0 + 8) = c;
    }
    __syncthreads();
    const bf16x8 qf0 = *(const bf16x8*)(Qs + (wave * 16 + lr) * APAD + (quad << 3));
    const bf16x8 qf1 = *(const bf16x8*)(Qs + (wave * 16 + lr) * APAD + 32 + (quad << 3));

    const float slope = exp2f(-0.5f * (float)h);
    const int qpos = q0 + wave * 16 + quad * 4;   // +r
    float mrow[4] = {-INFINITY, -INFINITY, -INFINITY, -INFINITY};
    float lrow[4] = {0.f, 0.f, 0.f, 0.f};
    f32x4 oacc[4] = {};

    for (int kt0 = 0; kt0 < SEQ; kt0 += ATK) {
        __syncthreads();
        // ---- stage K tile
        {
            const float* p = kg + (size_t)(b * SEQ + kt0 + srow) * LDQ + hoff + sc0;
            float4 v0 = *(const float4*)(p);
            float4 v1 = *(const float4*)(p + 4);
            float4 v2 = *(const float4*)(p + 8);
            float4 v3 = *(const float4*)(p + 12);
            bf16x8 a, c;
            a[0] = f2bf(v0.x); a[1] = f2bf(v0.y); a[2] = f2bf(v0.z); a[3] = f2bf(v0.w);
            a[4] = f2bf(v1.x); a[5] = f2bf(v1.y); a[6] = f2bf(v1.z); a[7] = f2bf(v1.w);
            c[0] = f2bf(v2.x); c[1] = f2bf(v2.y); c[2] = f2bf(v2.z); c[3] = f2bf(v2.w);
            c[4] = f2bf(v3.x); c[5] = f2bf(v3.y); c[6] = f2bf(v3.z); c[7] = f2bf(v3.w);
            *(bf16x8*)(Ks + srow * APAD + sc0) = a;
            *(bf16x8*)(Ks + srow * APAD + sc0 + 8) = c;
        }
        // ---- stage V tile transposed: Vt[hd][key]
        {
            const float* p = vg + (size_t)(b * SEQ + kt0 + srow) * LDQ + hoff + sc0;
            float4 v0 = *(const float4*)(p);
            float4 v1 = *(const float4*)(p + 4);
            float4 v2 = *(const float4*)(p + 8);
            float4 v3 = *(const float4*)(p + 12);
            float a[16] = {v0.x, v0.y, v0.z, v0.w, v1.x, v1.y, v1.z, v1.w,
                           v2.x, v2.y, v2.z, v2.w, v3.x, v3.y, v3.z, v3.w};
#pragma unroll
            for (int i = 0; i < 16; ++i)
                Vt[(sc0 + i) * APAD + srow] = (short)f2bf(a[i]);
        }
        __syncthreads();

        // ---- S = Q K^T  (4 j-tiles of 16 keys)
        f32x4 s[4] = {};
#pragma unroll
        for (int j = 0; j < 4; ++j) {
            bf16x8 b0 = *(const bf16x8*)(Ks + (j * 16 + lr) * APAD + (quad << 3));
            bf16x8 b1 = *(const bf16x8*)(Ks + (j * 16 + lr) * APAD + 32 + (quad << 3));
            s[j] = __builtin_amdgcn_mfma_f32_16x16x32_bf16(qf0, b0, s[j], 0, 0, 0);
            s[j] = __builtin_amdgcn_mfma_f32_16x16x32_bf16(qf1, b1, s[j], 0, 0, 0);
        }

        // ---- bias + online softmax (rows quad*4+r, cols j*16+lr)
        float pv[4][4];
        float rmax[4] = {-INFINITY, -INFINITY, -INFINITY, -INFINITY};
#pragma unroll
        for (int j = 0; j < 4; ++j) {
            const int kpos = kt0 + j * 16 + lr;
#pragma unroll
            for (int r = 0; r < 4; ++r) {
                float dist = (float)(qpos + r - kpos);
                float val = s[j][r] * 0.125f + slope * fmaxf(dist, 0.0f);
                pv[j][r] = val;
                rmax[r] = fmaxf(rmax[r], val);
            }
        }
#pragma unroll
        for (int off = 1; off <= 8; off <<= 1) {
#pragma unroll
            for (int r = 0; r < 4; ++r)
                rmax[r] = fmaxf(rmax[r], __shfl_xor(rmax[r], off));
        }
        float alpha[4], rsum[4] = {0.f, 0.f, 0.f, 0.f};
#pragma unroll
        for (int r = 0; r < 4; ++r) {
            float mnew = fmaxf(mrow[r], rmax[r]);
            alpha[r] = __expf(mrow[r] - mnew);
            mrow[r] = mnew;
        }
#pragma unroll
        for (int j = 0; j < 4; ++j)
#pragma unroll
            for (int r = 0; r < 4; ++r) {
                float e = __expf(pv[j][r] - mrow[r]);
                pv[j][r] = e;
                rsum[r] += e;
            }
#pragma unroll
        for (int off = 1; off <= 8; off <<= 1) {
#pragma unroll
            for (int r = 0; r < 4; ++r)
                rsum[r] += __shfl_xor(rsum[r], off);
        }
#pragma unroll
        for (int r = 0; r < 4; ++r)
            lrow[r] = lrow[r] * alpha[r] + rsum[r];
#pragma unroll
        for (int n = 0; n < 4; ++n)
#pragma unroll
            for (int r = 0; r < 4; ++r)
                oacc[n][r] *= alpha[r];

        // ---- P -> LDS (C-layout -> A-operand layout round trip)
#pragma unroll
        for (int j = 0; j < 4; ++j)
#pragma unroll
            for (int r = 0; r < 4; ++r)
                Ps[(wave * 16 + quad * 4 + r) * APAD + j * 16 + lr] = (short)f2bf(pv[j][r]);
        __syncthreads();

        // ---- O += P V
        bf16x8 p0 = *(const bf16x8*)(Ps + (wave * 16 + lr) * APAD + (quad << 3));
        bf16x8 p1 = *(const bf16x8*)(Ps + (wave * 16 + lr) * APAD + 32 + (quad << 3));
#pragma unroll
        for (int n = 0; n < 4; ++n) {
            bf16x8 b0 = *(const bf16x8*)(Vt + (n * 16 + lr) * APAD + (quad << 3));
            bf16x8 b1 = *(const bf16x8*)(Vt + (n * 16 + lr) * APAD + 32 + (quad << 3));
            oacc[n] = __builtin_amdgcn_mfma_f32_16x16x32_bf16(p0, b0, oacc[n], 0, 0, 0);
            oacc[n] = __builtin_amdgcn_mfma_f32_16x16x32_bf16(p1, b1, oacc[n], 0, 0, 0);
        }
    }

    // ---- epilogue: normalize, write bf16
    float inv[4];
#pragma unroll
    for (int r = 0; r < 4; ++r) inv[r] = 1.0f / lrow[r];
#pragma unroll
    for (int n = 0; n < 4; ++n)
#pragma unroll
        for (int r = 0; r < 4; ++r)
            ob[(size_t)(b * SEQ + qpos + r) * DMODEL + hoff + n * 16 + lr] =
                (short)f2bf(oacc[n][r] * inv[r]);
}

// ---------------------------------------------------------------- residual + LayerNorm (+ bf16 mirror)
__global__ __launch_bounds__(256) void add_ln_kernel(
    const float* __restrict__ x, const float* __restrict__ r,
    const float* __restrict__ g, const float* __restrict__ b,
    float* __restrict__ out, short* __restrict__ outb)
{
    __shared__ float rs[4], rq[4], stats[2];
    const int row = blockIdx.x, tid = threadIdx.x;
    const int c = tid << 2;
    float4 v = *(const float4*)(x + (size_t)row * DMODEL + c);
    if (r) {
        float4 rv = *(const float4*)(r + (size_t)row * DMODEL + c);
        v.x += rv.x; v.y += rv.y; v.z += rv.z; v.w += rv.w;
    }
    float s = v.x + v.y + v.z + v.w;
    float q2 = v.x * v.x + v.y * v.y + v.z * v.z + v.w * v.w;
#pragma unroll
    for (int off = 32; off; off >>= 1) {
        s += __shfl_down(s, off, 64);
        q2 += __shfl_down(q2, off, 64);
    }
    const int wid = tid >> 6, lane = tid & 63;
    if (lane == 0) { rs[wid] = s; rq[wid] = q2; }
    __syncthreads();
    if (tid == 0) {
        float ts = rs[0] + rs[1] + rs[2] + rs[3];
        float tq = rq[0] + rq[1] + rq[2] + rq[3];
        float mean = ts * (1.0f / DMODEL);
        stats[0] = mean;
        stats[1] = rsqrtf(tq * (1.0f / DMODEL) - mean * mean + LNEPS);
    }
    __syncthreads();
    const float mean = stats[0], rstd = stats[1];
    float4 gv = *(const float4*)(g + c);
    float4 bv = *(const float4*)(b + c);
    float4 res;
    res.x = (v.x - mean) * rstd * gv.x + bv.x;
    res.y = (v.y - mean) * rstd * gv.y + bv.y;
    res.z = (v.z - mean) * rstd * gv.z + bv.z;
    res.w = (v.w - mean) * rstd * gv.w + bv.w;
    *(float4*)(out + (size_t)row * DMODEL + c) = res;
    if (outb) {
        uint2 p;
        p.x = (unsigned)f2bf(res.x) | ((unsigned)f2bf(res.y) << 16);
        p.y = (unsigned)f2bf(res.z) | ((unsigned)f2bf(res.w) << 16);
        *(uint2*)(outb + (size_t)row * DMODEL + c) = p;
    }
}

// ---------------------------------------------------------------- host
extern "C" void kernel_launch(void* const* d_in, const int* in_sizes, int n_in,
                              void* d_out, int out_size, void* d_ws, size_t ws_size,
                              hipStream_t stream)
{
    (void)in_sizes; (void)n_in; (void)out_size; (void)ws_size;
    const float* src = (const float*)d_in[0];
    const float* Wq  = (const float*)d_in[1];
    const float* bq  = (const float*)d_in[2];
    const float* Wk  = (const float*)d_in[3];
    const float* bk  = (const float*)d_in[4];
    const float* Wv  = (const float*)d_in[5];
    const float* bv  = (const float*)d_in[6];
    const float* Wo  = (const float*)d_in[7];
    const float* bo  = (const float*)d_in[8];
    const float* W1  = (const float*)d_in[9];
    const float* b1  = (const float*)d_in[10];
    const float* W2  = (const float*)d_in[11];
    const float* b2  = (const float*)d_in[12];
    const float* g1  = (const float*)d_in[13];
    const float* be1 = (const float*)d_in[14];
    const float* g2  = (const float*)d_in[15];
    const float* be2 = (const float*)d_in[16];
    const float* gf  = (const float*)d_in[17];
    const float* bfp = (const float*)d_in[18];
    float* out = (float*)d_out;

    char* p = (char*)d_ws;
    auto carve = [&](size_t bytes) -> char* {
        char* r = p; p += (bytes + 255) & ~(size_t)255; return r;
    };
    float* x    = (float*)carve((size_t)MROWS * DMODEL * 4);
    float* t1   = (float*)carve((size_t)MROWS * DMODEL * 4);
    float* xqkv = (float*)carve((size_t)MROWS * LDQ * 4);
    float* pe   = (float*)carve((size_t)SEQ * HD * 4);
    float* bqkv = (float*)carve((size_t)LDQ * 4);
    short* xb   = (short*)carve((size_t)MROWS * DMODEL * 2);
    short* obb  = (short*)carve((size_t)MROWS * DMODEL * 2);
    short* h1b  = (short*)carve((size_t)MROWS * FFD * 2);
    short* wtqkv= (short*)carve((size_t)3 * DMODEL * DMODEL * 2);
    short* wto  = (short*)carve((size_t)DMODEL * DMODEL * 2);
    short* wt1  = (short*)carve((size_t)DMODEL * FFD * 2);
    short* wt2  = (short*)carve((size_t)DMODEL * FFD * 2);

    hipMemcpyAsync(x, src, (size_t)MROWS * DMODEL * 4, hipMemcpyDeviceToDevice, stream);
    conv_bf16<<<MROWS * DMODEL / 4 / 256, 256, 0, stream>>>(src, xb, MROWS * DMODEL);
    pe_fill<<<SEQ, HD, 0, stream>>>(pe);

    const size_t DD = (size_t)DMODEL * DMODEL;
    for (int l = 0; l < NLAYERS; ++l) {
        transpose_bf16<<<dim3(32, 32), 256, 0, stream>>>(Wq + l * DD, wtqkv,          DMODEL, DMODEL);
        transpose_bf16<<<dim3(32, 32), 256, 0, stream>>>(Wk + l * DD, wtqkv + DD,     DMODEL, DMODEL);
        transpose_bf16<<<dim3(32, 32), 256, 0, stream>>>(Wv + l * DD, wtqkv + 2 * DD, DMODEL, DMODEL);
        transpose_bf16<<<dim3(32, 32), 256, 0, stream>>>(Wo + l * DD, wto, DMODEL, DMODEL);
        transpose_bf16<<<dim3(128, 32), 256, 0, stream>>>(W1 + (size_t)l * DMODEL * FFD, wt1, DMODEL, FFD);
        transpose_bf16<<<dim3(32, 128), 256, 0, stream>>>(W2 + (size_t)l * FFD * DMODEL, wt2, FFD, DMODEL);
        stack_bias<<<12, 256, 0, stream>>>(bq + l * DMODEL, bk + l * DMODEL, bv + l * DMODEL, bqkv);

        gemm_tn<<<dim3(LDQ / TNT, MROWS / TMT), 256, 0, stream>>>(
            xb, wtqkv, bqkv, xqkv, nullptr, MROWS, LDQ, DMODEL, LDQ, 0);
        rope_kernel<<<dim3(MROWS * NH, 2), 64, 0, stream>>>(xqkv, pe);
        attn_mfma<<<BATCH * NH * (SEQ / ATQ), 256, 0, stream>>>(xqkv, obb);
        gemm_tn<<<dim3(DMODEL / TNT, MROWS / TMT), 256, 0, stream>>>(
            obb, wto, bo + l * DMODEL, t1, nullptr, MROWS, DMODEL, DMODEL, DMODEL, 0);
        add_ln_kernel<<<MROWS, 256, 0, stream>>>(x, t1, g1 + l * DMODEL, be1 + l * DMODEL, x, xb);
        gemm_tn<<<dim3(FFD / TNT, MROWS / TMT), 256, 0, stream>>>(
            xb, wt1, b1 + l * FFD, nullptr, h1b, MROWS, FFD, DMODEL, FFD, 1);
        gemm_tn<<<dim3(DMODEL / TNT, MROWS / TMT), 256, 0, stream>>>(
            h1b, wt2, b2 + l * DMODEL, t1, nullptr, MROWS, DMODEL, FFD, DMODEL, 0);
        add_ln_kernel<<<MROWS, 256, 0, stream>>>(x, t1, g2 + l * DMODEL, be2 + l * DMODEL, x, xb);
    }
    add_ln_kernel<<<MROWS, 256, 0, stream>>>(x, nullptr, gf, bfp, out, nullptr);
}